// Round 2
// baseline (1250.859 us; speedup 1.0000x reference)
//
#include <hip/hip_runtime.h>

typedef unsigned short ushort_t;
typedef __bf16 bf16_t;
typedef bf16_t bf16x8 __attribute__((ext_vector_type(8)));
typedef float floatx4 __attribute__((ext_vector_type(4)));
typedef ushort_t ushort4v __attribute__((ext_vector_type(4)));
typedef ushort_t ushort8v __attribute__((ext_vector_type(8)));

static constexpr int B = 2, S = 2048, D = 2048;
static constexpr int H = 16, KVH = 4, HD = 256;

#define DEVFN static __device__ __forceinline__

DEVFN ushort_t f2b(float f) {
  union { float f; unsigned u; } x; x.f = f;
  unsigned r = x.u + 0x7fffu + ((x.u >> 16) & 1u);
  return (ushort_t)(r >> 16);
}
DEVFN float b2f(ushort_t h) {
  union { unsigned u; float f; } x; x.u = ((unsigned)h) << 16;
  return x.f;
}
DEVFN void gll16(const void* g, void* l) {
  __builtin_amdgcn_global_load_lds(
      (const __attribute__((address_space(1))) void*)g,
      (__attribute__((address_space(3))) void*)l, 16, 0, 0);
}

// ---------------------------------------------------------------- conversions
__global__ void k_cvt_bf16(const float* __restrict__ in, ushort_t* __restrict__ out, int n) {
  int i = (blockIdx.x * 256 + threadIdx.x) * 4;
  if (i >= n) return;
  float4 v = *(const float4*)(in + i);
  ushort4v o;
  o[0] = f2b(v.x); o[1] = f2b(v.y); o[2] = f2b(v.z); o[3] = f2b(v.w);
  *(ushort4v*)(out + i) = o;
}

// in: R x C fp32 row-major; out: C x R bf16 row-major (out[c][r] = in[r][c])
__global__ void k_transpose_cvt(const float* __restrict__ in, ushort_t* __restrict__ out,
                                int R, int C) {
  __shared__ float tile[32][33];
  const int bx = blockIdx.x * 32, by = blockIdx.y * 32;
  const int tx = threadIdx.x, ty = threadIdx.y;
#pragma unroll
  for (int i = 0; i < 32; i += 8)
    tile[ty + i][tx] = in[(size_t)(by + ty + i) * C + bx + tx];
  __syncthreads();
#pragma unroll
  for (int i = 0; i < 32; i += 8)
    out[(size_t)(bx + ty + i) * R + by + tx] = f2b(tile[tx][ty + i]);
}

// cos/sin table: tab[(s*128+dd)*2] = cos, +1 = sin
__global__ void k_rope_table(const int* __restrict__ pos_ids, float* __restrict__ tab) {
  int idx = blockIdx.x * 256 + threadIdx.x;  // S*128 total
  int s = idx >> 7, dd = idx & 127;
  float ang = (float)pos_ids[s] * exp2f((float)dd * (-13.287712379549449f / 128.0f));
  tab[idx * 2] = cosf(ang);
  tab[idx * 2 + 1] = sinf(ang);
}

// ---------------------------------------------------------------- GEMM (A row-major MxK, Bt row-major NxK)
// MODE 0: bf16 row-major to C0. MODE 1: fp32 row-major to C0.
// MODE 3: fused KV — cols [0,1024) -> K bf16 row-major (ld 1024) to C0;
//         cols [1024,2048) -> V transposed to C1 as Vt[(b*KVH+kvh)*HD+hd][s].
template <int MODE>
__global__ __launch_bounds__(256, 2)
void k_gemm_bt(const ushort_t* __restrict__ A, const ushort_t* __restrict__ Bt,
               void* __restrict__ C0, void* __restrict__ C1, int M, int N, int K) {
  __shared__ ushort_t As[128 * 32];
  __shared__ ushort_t Bs[128 * 32];
  const int lane = threadIdx.x & 63;
  const int wave = threadIdx.x >> 6;
  const int lr = lane & 15, lq = lane >> 4;
  const size_t m0 = (size_t)blockIdx.x * 128;
  const size_t n0 = (size_t)blockIdx.y * 128;
  const int wm = (wave & 1) * 4;
  const int wn = (wave >> 1) * 4;

  floatx4 acc[4][4];
#pragma unroll
  for (int i = 0; i < 4; i++)
#pragma unroll
    for (int j = 0; j < 4; j++) acc[i][j] = {0.f, 0.f, 0.f, 0.f};

  for (int kt = 0; kt < K; kt += 32) {
    __syncthreads();
#pragma unroll
    for (int i = 0; i < 2; i++) {
      const int c = wave * 2 + i;
      gll16(A + (m0 + c * 16 + lr) * K + kt + lq * 8, &As[c * 512 + lane * 8]);
      gll16(Bt + (n0 + c * 16 + lr) * K + kt + lq * 8, &Bs[c * 512 + lane * 8]);
    }
    __syncthreads();
    bf16x8 af[4], bfv[4];
#pragma unroll
    for (int i = 0; i < 4; i++) af[i] = *(const bf16x8*)&As[(wm + i) * 512 + lane * 8];
#pragma unroll
    for (int j = 0; j < 4; j++) bfv[j] = *(const bf16x8*)&Bs[(wn + j) * 512 + lane * 8];
#pragma unroll
    for (int i = 0; i < 4; i++)
#pragma unroll
      for (int j = 0; j < 4; j++)
        acc[i][j] = __builtin_amdgcn_mfma_f32_16x16x32_bf16(af[i], bfv[j], acc[i][j], 0, 0, 0);
  }

#pragma unroll
  for (int i = 0; i < 4; i++)
#pragma unroll
    for (int j = 0; j < 4; j++)
#pragma unroll
      for (int r = 0; r < 4; r++) {
        size_t row = m0 + (size_t)(wm + i) * 16 + lq * 4 + r;
        size_t col = n0 + (size_t)(wn + j) * 16 + lr;
        float v = acc[i][j][r];
        if (MODE == 0) {
          ((ushort_t*)C0)[row * N + col] = f2b(v);
        } else if (MODE == 1) {
          ((float*)C0)[row * N + col] = v;
        } else {  // MODE 3
          if (col < 1024) {
            ((ushort_t*)C0)[row * 1024 + col] = f2b(v);
          } else {
            size_t c = col - 1024;
            size_t bb = row >> 11, ss = row & 2047;
            ((ushort_t*)C1)[((bb * KVH + (c >> 8)) * HD + (c & 255)) * S + ss] = f2b(v);
          }
        }
      }
}

// ---------------------------------------------------------------- RMSNorm + RoPE (one wave per 256-row)
__global__ void k_norm_rope(ushort_t* __restrict__ x, const float* __restrict__ w,
                            const float* __restrict__ tab, int heads, float scale) {
  const int lane = threadIdx.x & 63;
  const size_t row = (size_t)blockIdx.x * 4 + (threadIdx.x >> 6);
  const int s = (int)((row / heads) % S);
  ushort_t* p = x + row * HD + lane * 4;
  ushort4v raw = *(const ushort4v*)p;
  float v[4];
  float ss = 0.f;
#pragma unroll
  for (int i = 0; i < 4; i++) { v[i] = b2f(raw[i]); ss += v[i] * v[i]; }
#pragma unroll
  for (int m = 1; m < 64; m <<= 1) ss += __shfl_xor(ss, m, 64);
  const float inv = rsqrtf(ss * (1.0f / HD) + 1e-6f);
  float4 wv = *(const float4*)(w + lane * 4);
  float y[4];
  y[0] = v[0] * inv * (1.0f + wv.x);
  y[1] = v[1] * inv * (1.0f + wv.y);
  y[2] = v[2] * inv * (1.0f + wv.z);
  y[3] = v[3] * inv * (1.0f + wv.w);
  float py[4];
#pragma unroll
  for (int i = 0; i < 4; i++) py[i] = __shfl_xor(y[i], 32, 64);
  const bool lo = (lane < 32);
  ushort4v ov;
#pragma unroll
  for (int i = 0; i < 4; i++) {
    int d = lane * 4 + i;
    int dd = d & 127;
    float2 cs = *(const float2*)(tab + ((size_t)s * 128 + dd) * 2);
    float rot = lo ? -py[i] : py[i];
    ov[i] = f2b((y[i] * cs.x + rot * cs.y) * scale);
  }
  *(ushort4v*)p = ov;
}

// ---------------------------------------------------------------- flash attention
// grid (S/64, H, B); block 256 = 4 waves x 16 q-rows; kv-tile 32
// K from Kb [b][s][kvh][hd]; V from Vt [(b*KVH+kvh)*HD+hd][s] (pre-transposed)
__global__ __launch_bounds__(256, 4)
void k_attn(const ushort_t* __restrict__ Q, const ushort_t* __restrict__ Kg,
            const ushort_t* __restrict__ Vt, ushort_t* __restrict__ O) {
  __shared__ ushort_t Ks[16 * 512];   // chunks c = nt*8+ks (nt 0..1 kv-rows, ks 0..7 hd)
  __shared__ ushort_t Vs[16 * 512];   // chunks f = hd-tile 0..15, fragment order
  __shared__ ushort_t Ps[4][16 * 40]; // per-wave P, row stride 40 ushorts
  const int lane = threadIdx.x & 63, wave = threadIdx.x >> 6;
  const int lr = lane & 15, lq = lane >> 4;
  const int qt = (int)gridDim.x - 1 - (int)blockIdx.x;  // heavy blocks first
  const int h = blockIdx.y, b = blockIdx.z;
  const int kvh = h >> 2;
  const int q0 = qt * 64 + wave * 16;
  const ushort_t* vtb = Vt + (size_t)(b * KVH + kvh) * HD * S;

  bf16x8 qf[8];
  {
    const ushort_t* qp = Q + ((size_t)(b * S + q0 + lr) * H + h) * HD + lq * 8;
#pragma unroll
    for (int ks = 0; ks < 8; ks++) qf[ks] = *(const bf16x8*)(qp + ks * 32);
  }
  floatx4 o[16];
#pragma unroll
  for (int f = 0; f < 16; f++) o[f] = {0.f, 0.f, 0.f, 0.f};
  float m_i[4] = {-1e30f, -1e30f, -1e30f, -1e30f};
  float l_i[4] = {0.f, 0.f, 0.f, 0.f};

  const int ntiles = (qt + 1) * 2;
  for (int kt = 0; kt < ntiles; kt++) {
    const int kbase = kt * 32;
    __syncthreads();  // previous tile's LDS reads done
#pragma unroll
    for (int i = 0; i < 8; i++) {
      const int c = wave * 8 + i;
      if (c < 16) {
        const int nt = c >> 3, ks = c & 7;
        gll16(Kg + ((size_t)(b * S + kbase + nt * 16 + lr) * KVH + kvh) * HD + ks * 32 + lq * 8,
              &Ks[c * 512 + lane * 8]);
      } else {
        const int f = c - 16;
        gll16(vtb + (size_t)(f * 16 + lr) * S + kbase + lq * 8, &Vs[f * 512 + lane * 8]);
      }
    }
    __syncthreads();  // staging drained
    if (kbase > q0 + 15) continue;
    const int ntmax = min(2, ((q0 + 15 - kbase) >> 4) + 1);

    floatx4 sacc[2];
#pragma unroll
    for (int nt = 0; nt < 2; nt++) {
      if (nt < ntmax) {
        sacc[nt] = {0.f, 0.f, 0.f, 0.f};
#pragma unroll
        for (int ks = 0; ks < 8; ks++) {
          bf16x8 kf = *(const bf16x8*)&Ks[(nt * 8 + ks) * 512 + lane * 8];
          sacc[nt] = __builtin_amdgcn_mfma_f32_16x16x32_bf16(qf[ks], kf, sacc[nt], 0, 0, 0);
        }
      } else {
        sacc[nt] = {-1e30f, -1e30f, -1e30f, -1e30f};
      }
    }
    if (kbase + 31 > q0) {  // causal mask (log2-domain scores)
#pragma unroll
      for (int nt = 0; nt < 2; nt++)
        if (nt < ntmax)
#pragma unroll
          for (int r = 0; r < 4; r++)
            if (kbase + nt * 16 + lr > q0 + lq * 4 + r) sacc[nt][r] = -1e30f;
    }
    float mt[4], alpha[4], rs[4];
#pragma unroll
    for (int r = 0; r < 4; r++) mt[r] = fmaxf(sacc[0][r], sacc[1][r]);
#pragma unroll
    for (int m = 1; m < 16; m <<= 1)
#pragma unroll
      for (int r = 0; r < 4; r++) mt[r] = fmaxf(mt[r], __shfl_xor(mt[r], m, 64));
#pragma unroll
    for (int r = 0; r < 4; r++) {
      float mn = fmaxf(m_i[r], mt[r]);
      alpha[r] = exp2f(m_i[r] - mn);
      m_i[r] = mn;
    }
#pragma unroll
    for (int nt = 0; nt < 2; nt++)
#pragma unroll
      for (int r = 0; r < 4; r++) sacc[nt][r] = exp2f(sacc[nt][r] - m_i[r]);
#pragma unroll
    for (int r = 0; r < 4; r++) rs[r] = sacc[0][r] + sacc[1][r];
#pragma unroll
    for (int m = 1; m < 16; m <<= 1)
#pragma unroll
      for (int r = 0; r < 4; r++) rs[r] += __shfl_xor(rs[r], m, 64);
#pragma unroll
    for (int r = 0; r < 4; r++) l_i[r] = l_i[r] * alpha[r] + rs[r];
#pragma unroll
    for (int f = 0; f < 16; f++) {
      o[f][0] *= alpha[0]; o[f][1] *= alpha[1];
      o[f][2] *= alpha[2]; o[f][3] *= alpha[3];
    }
    // P: C-layout -> LDS -> A-layout (per-wave buffer, no barrier needed)
    ushort_t* psw = Ps[wave];
#pragma unroll
    for (int nt = 0; nt < 2; nt++)
#pragma unroll
      for (int r = 0; r < 4; r++)
        psw[(lq * 4 + r) * 40 + nt * 16 + lr] = f2b(sacc[nt][r]);
    bf16x8 pf = *(const bf16x8*)&psw[lr * 40 + lq * 8];
#pragma unroll
    for (int f = 0; f < 16; f++) {
      bf16x8 vf = *(const bf16x8*)&Vs[f * 512 + lane * 8];
      o[f] = __builtin_amdgcn_mfma_f32_16x16x32_bf16(pf, vf, o[f], 0, 0, 0);
    }
  }
  float invl[4];
#pragma unroll
  for (int r = 0; r < 4; r++) invl[r] = 1.0f / l_i[r];
#pragma unroll
  for (int f = 0; f < 16; f++)
#pragma unroll
    for (int r = 0; r < 4; r++)
      O[((size_t)(b * S + q0 + lq * 4 + r) * H + h) * HD + f * 16 + lr] =
          f2b(o[f][r] * invl[r]);
}

// ---------------------------------------------------------------- launch
extern "C" void kernel_launch(void* const* d_in, const int* in_sizes, int n_in,
                              void* d_out, int out_size, void* d_ws, size_t ws_size,
                              hipStream_t stream) {
  const float* hs = (const float*)d_in[0];
  const float* Wq = (const float*)d_in[1];
  const float* Wk = (const float*)d_in[2];
  const float* Wv = (const float*)d_in[3];
  const float* Wo = (const float*)d_in[4];
  const float* qw = (const float*)d_in[5];
  const float* kw = (const float*)d_in[6];
  const int* pos = (const int*)d_in[7];
  float* out = (float*)d_out;

  char* ws = (char*)d_ws;
  size_t off = 0;
  auto alloc = [&](size_t bytes) {
    void* p = ws + off;
    off += (bytes + 255) & ~(size_t)255;
    return p;
  };
  ushort_t* Xb   = (ushort_t*)alloc((size_t)B * S * D * 2);
  ushort_t* Wqt  = (ushort_t*)alloc((size_t)(H * HD) * D * 2);
  ushort_t* Wkvt = (ushort_t*)alloc((size_t)(2 * KVH * HD) * D * 2);  // K rows then V rows
  ushort_t* Wot  = (ushort_t*)alloc((size_t)D * (H * HD) * 2);
  ushort_t* Qb   = (ushort_t*)alloc((size_t)B * S * H * HD * 2);
  ushort_t* Kb   = (ushort_t*)alloc((size_t)B * S * KVH * HD * 2);
  ushort_t* Vt   = (ushort_t*)alloc((size_t)B * KVH * HD * S * 2);
  ushort_t* Ab   = (ushort_t*)alloc((size_t)B * S * H * HD * 2);
  float*    tab  = (float*)alloc((size_t)S * 128 * 2 * sizeof(float));

  k_cvt_bf16<<<(B * S * D / 4 + 255) / 256, 256, 0, stream>>>(hs, Xb, B * S * D);
  k_transpose_cvt<<<dim3((H * HD) / 32, D / 32), dim3(32, 8), 0, stream>>>(Wq, Wqt, D, H * HD);
  k_transpose_cvt<<<dim3((KVH * HD) / 32, D / 32), dim3(32, 8), 0, stream>>>(Wk, Wkvt, D, KVH * HD);
  k_transpose_cvt<<<dim3((KVH * HD) / 32, D / 32), dim3(32, 8), 0, stream>>>(
      Wv, Wkvt + (size_t)(KVH * HD) * D, D, KVH * HD);
  k_transpose_cvt<<<dim3(D / 32, (H * HD) / 32), dim3(32, 8), 0, stream>>>(Wo, Wot, H * HD, D);
  k_rope_table<<<S * 128 / 256, 256, 0, stream>>>(pos, tab);

  k_gemm_bt<0><<<dim3(B * S / 128, (H * HD) / 128), 256, 0, stream>>>(
      Xb, Wqt, Qb, nullptr, B * S, H * HD, D);
  k_gemm_bt<3><<<dim3(B * S / 128, (2 * KVH * HD) / 128), 256, 0, stream>>>(
      Xb, Wkvt, Kb, Vt, B * S, 2 * KVH * HD, D);

  // Q scale folds 1/sqrt(HD)=1/16 AND log2(e) (softmax done in exp2 domain)
  k_norm_rope<<<B * S * H / 4, 256, 0, stream>>>(Qb, qw, tab, H, 0.0625f * 1.4426950408889634f);
  k_norm_rope<<<B * S * KVH / 4, 256, 0, stream>>>(Kb, kw, tab, KVH, 1.0f);

  k_attn<<<dim3(S / 64, H, B), 256, 0, stream>>>(Qb, Kb, Vt, Ab);

  k_gemm_bt<1><<<dim3(B * S / 128, D / 128), 256, 0, stream>>>(
      Ab, Wot, out, nullptr, B * S, D, H * HD);
}

// Round 3
// 942.616 us; speedup vs baseline: 1.3270x; 1.3270x over previous
//
#include <hip/hip_runtime.h>

typedef unsigned short ushort_t;
typedef __bf16 bf16_t;
typedef bf16_t bf16x8 __attribute__((ext_vector_type(8)));
typedef float floatx4 __attribute__((ext_vector_type(4)));
typedef ushort_t ushort4v __attribute__((ext_vector_type(4)));
typedef ushort_t ushort8v __attribute__((ext_vector_type(8)));

static constexpr int B = 2, S = 2048, D = 2048;
static constexpr int H = 16, KVH = 4, HD = 256;

#define DEVFN static __device__ __forceinline__

DEVFN ushort_t f2b(float f) {
  union { float f; unsigned u; } x; x.f = f;
  unsigned r = x.u + 0x7fffu + ((x.u >> 16) & 1u);
  return (ushort_t)(r >> 16);
}
DEVFN float b2f(ushort_t h) {
  union { unsigned u; float f; } x; x.u = ((unsigned)h) << 16;
  return x.f;
}
DEVFN void gll16(const void* g, void* l) {
  __builtin_amdgcn_global_load_lds(
      (const __attribute__((address_space(1))) void*)g,
      (__attribute__((address_space(3))) void*)l, 16, 0, 0);
}

// ---------------------------------------------------------------- conversions
__global__ void k_cvt_bf16(const float* __restrict__ in, ushort_t* __restrict__ out, int n) {
  int i = (blockIdx.x * 256 + threadIdx.x) * 4;
  if (i >= n) return;
  float4 v = *(const float4*)(in + i);
  ushort4v o;
  o[0] = f2b(v.x); o[1] = f2b(v.y); o[2] = f2b(v.z); o[3] = f2b(v.w);
  *(ushort4v*)(out + i) = o;
}

// in: R x C fp32 row-major; out: C x R bf16 row-major (out[c][r] = in[r][c])
__global__ void k_transpose_cvt(const float* __restrict__ in, ushort_t* __restrict__ out,
                                int R, int C) {
  __shared__ float tile[32][33];
  const int bx = blockIdx.x * 32, by = blockIdx.y * 32;
  const int tx = threadIdx.x, ty = threadIdx.y;
#pragma unroll
  for (int i = 0; i < 32; i += 8)
    tile[ty + i][tx] = in[(size_t)(by + ty + i) * C + bx + tx];
  __syncthreads();
#pragma unroll
  for (int i = 0; i < 32; i += 8)
    out[(size_t)(bx + ty + i) * R + by + tx] = f2b(tile[tx][ty + i]);
}

// cos/sin table: tab[(s*128+dd)*2] = cos, +1 = sin
__global__ void k_rope_table(const int* __restrict__ pos_ids, float* __restrict__ tab) {
  int idx = blockIdx.x * 256 + threadIdx.x;  // S*128 total
  int s = idx >> 7, dd = idx & 127;
  float ang = (float)pos_ids[s] * exp2f((float)dd * (-13.287712379549449f / 128.0f));
  tab[idx * 2] = cosf(ang);
  tab[idx * 2 + 1] = sinf(ang);
}

// ---------------------------------------------------------------- GEMM (A row-major MxK, Bt row-major NxK)
// MODE 0: bf16 row-major to C0. MODE 1: fp32 row-major to C0.
// MODE 3: fused KV — cols [0,1024) -> K bf16 row-major (ld 1024) to C0;
//         cols [1024,2048) -> V transposed to C1 as Vt[(b*KVH+kvh)*HD+hd][s].
template <int MODE>
__global__ __launch_bounds__(256, 2)
void k_gemm_bt(const ushort_t* __restrict__ A, const ushort_t* __restrict__ Bt,
               void* __restrict__ C0, void* __restrict__ C1, int M, int N, int K) {
  __shared__ ushort_t As[128 * 32];
  __shared__ ushort_t Bs[128 * 32];
  const int lane = threadIdx.x & 63;
  const int wave = threadIdx.x >> 6;
  const int lr = lane & 15, lq = lane >> 4;
  const size_t m0 = (size_t)blockIdx.x * 128;
  const size_t n0 = (size_t)blockIdx.y * 128;
  const int wm = (wave & 1) * 4;
  const int wn = (wave >> 1) * 4;

  floatx4 acc[4][4];
#pragma unroll
  for (int i = 0; i < 4; i++)
#pragma unroll
    for (int j = 0; j < 4; j++) acc[i][j] = {0.f, 0.f, 0.f, 0.f};

  for (int kt = 0; kt < K; kt += 32) {
    __syncthreads();
#pragma unroll
    for (int i = 0; i < 2; i++) {
      const int c = wave * 2 + i;
      gll16(A + (m0 + c * 16 + lr) * K + kt + lq * 8, &As[c * 512 + lane * 8]);
      gll16(Bt + (n0 + c * 16 + lr) * K + kt + lq * 8, &Bs[c * 512 + lane * 8]);
    }
    __syncthreads();
    bf16x8 af[4], bfv[4];
#pragma unroll
    for (int i = 0; i < 4; i++) af[i] = *(const bf16x8*)&As[(wm + i) * 512 + lane * 8];
#pragma unroll
    for (int j = 0; j < 4; j++) bfv[j] = *(const bf16x8*)&Bs[(wn + j) * 512 + lane * 8];
#pragma unroll
    for (int i = 0; i < 4; i++)
#pragma unroll
      for (int j = 0; j < 4; j++)
        acc[i][j] = __builtin_amdgcn_mfma_f32_16x16x32_bf16(af[i], bfv[j], acc[i][j], 0, 0, 0);
  }

#pragma unroll
  for (int i = 0; i < 4; i++)
#pragma unroll
    for (int j = 0; j < 4; j++)
#pragma unroll
      for (int r = 0; r < 4; r++) {
        size_t row = m0 + (size_t)(wm + i) * 16 + lq * 4 + r;
        size_t col = n0 + (size_t)(wn + j) * 16 + lr;
        float v = acc[i][j][r];
        if (MODE == 0) {
          ((ushort_t*)C0)[row * N + col] = f2b(v);
        } else if (MODE == 1) {
          ((float*)C0)[row * N + col] = v;
        } else {  // MODE 3
          if (col < 1024) {
            ((ushort_t*)C0)[row * 1024 + col] = f2b(v);
          } else {
            size_t c = col - 1024;
            size_t bb = row >> 11, ss = row & 2047;
            ((ushort_t*)C1)[((bb * KVH + (c >> 8)) * HD + (c & 255)) * S + ss] = f2b(v);
          }
        }
      }
}

// ---------------------------------------------------------------- RMSNorm + RoPE (one wave per 256-row)
__global__ void k_norm_rope(ushort_t* __restrict__ x, const float* __restrict__ w,
                            const float* __restrict__ tab, int heads, float scale) {
  const int lane = threadIdx.x & 63;
  const size_t row = (size_t)blockIdx.x * 4 + (threadIdx.x >> 6);
  const int s = (int)((row / heads) % S);
  ushort_t* p = x + row * HD + lane * 4;
  ushort4v raw = *(const ushort4v*)p;
  float v[4];
  float ss = 0.f;
#pragma unroll
  for (int i = 0; i < 4; i++) { v[i] = b2f(raw[i]); ss += v[i] * v[i]; }
#pragma unroll
  for (int m = 1; m < 64; m <<= 1) ss += __shfl_xor(ss, m, 64);
  const float inv = rsqrtf(ss * (1.0f / HD) + 1e-6f);
  float4 wv = *(const float4*)(w + lane * 4);
  float y[4];
  y[0] = v[0] * inv * (1.0f + wv.x);
  y[1] = v[1] * inv * (1.0f + wv.y);
  y[2] = v[2] * inv * (1.0f + wv.z);
  y[3] = v[3] * inv * (1.0f + wv.w);
  float py[4];
#pragma unroll
  for (int i = 0; i < 4; i++) py[i] = __shfl_xor(y[i], 32, 64);
  const bool lo = (lane < 32);
  ushort4v ov;
#pragma unroll
  for (int i = 0; i < 4; i++) {
    int d = lane * 4 + i;
    int dd = d & 127;
    float2 cs = *(const float2*)(tab + ((size_t)s * 128 + dd) * 2);
    float rot = lo ? -py[i] : py[i];
    ov[i] = f2b((y[i] * cs.x + rot * cs.y) * scale);
  }
  *(ushort4v*)p = ov;
}

// ---------------------------------------------------------------- flash attention
// grid (S/64, H, B); block 256 = 4 waves x 16 q-rows; kv-tile 32
// K from Kb [b][s][kvh][hd]; V from Vt [(b*KVH+kvh)*HD+hd][s] (pre-transposed)
// launch_bounds(256,3): VGPR cap ~170 — (256,4) capped at 128 and SPILLED
// (r2: WRITE_SIZE +45MB scratch, dur 2x). Kernel needs ~150 unified regs.
__global__ __launch_bounds__(256, 3)
void k_attn(const ushort_t* __restrict__ Q, const ushort_t* __restrict__ Kg,
            const ushort_t* __restrict__ Vt, ushort_t* __restrict__ O) {
  __shared__ ushort_t Ks[16 * 512];   // chunks c = nt*8+ks (nt 0..1 kv-rows, ks 0..7 hd)
  __shared__ ushort_t Vs[16 * 512];   // chunks f = hd-tile 0..15, fragment order
  __shared__ ushort_t Ps[4][16 * 40]; // per-wave P, row stride 40 ushorts
  const int lane = threadIdx.x & 63, wave = threadIdx.x >> 6;
  const int lr = lane & 15, lq = lane >> 4;
  const int qt = (int)gridDim.x - 1 - (int)blockIdx.x;  // heavy blocks first
  const int h = blockIdx.y, b = blockIdx.z;
  const int kvh = h >> 2;
  const int q0 = qt * 64 + wave * 16;
  const ushort_t* vtb = Vt + (size_t)(b * KVH + kvh) * HD * S;

  bf16x8 qf[8];
  {
    const ushort_t* qp = Q + ((size_t)(b * S + q0 + lr) * H + h) * HD + lq * 8;
#pragma unroll
    for (int ks = 0; ks < 8; ks++) qf[ks] = *(const bf16x8*)(qp + ks * 32);
  }
  floatx4 o[16];
#pragma unroll
  for (int f = 0; f < 16; f++) o[f] = {0.f, 0.f, 0.f, 0.f};
  float m_i[4] = {-1e30f, -1e30f, -1e30f, -1e30f};
  float l_i[4] = {0.f, 0.f, 0.f, 0.f};

  const int ntiles = (qt + 1) * 2;
  for (int kt = 0; kt < ntiles; kt++) {
    const int kbase = kt * 32;
    __syncthreads();  // previous tile's LDS reads done
#pragma unroll
    for (int i = 0; i < 8; i++) {
      const int c = wave * 8 + i;
      if (c < 16) {
        const int nt = c >> 3, ks = c & 7;
        gll16(Kg + ((size_t)(b * S + kbase + nt * 16 + lr) * KVH + kvh) * HD + ks * 32 + lq * 8,
              &Ks[c * 512 + lane * 8]);
      } else {
        const int f = c - 16;
        gll16(vtb + (size_t)(f * 16 + lr) * S + kbase + lq * 8, &Vs[f * 512 + lane * 8]);
      }
    }
    __syncthreads();  // staging drained
    if (kbase > q0 + 15) continue;
    const int ntmax = min(2, ((q0 + 15 - kbase) >> 4) + 1);

    floatx4 sacc[2];
#pragma unroll
    for (int nt = 0; nt < 2; nt++) {
      if (nt < ntmax) {
        sacc[nt] = {0.f, 0.f, 0.f, 0.f};
#pragma unroll
        for (int ks = 0; ks < 8; ks++) {
          bf16x8 kf = *(const bf16x8*)&Ks[(nt * 8 + ks) * 512 + lane * 8];
          sacc[nt] = __builtin_amdgcn_mfma_f32_16x16x32_bf16(qf[ks], kf, sacc[nt], 0, 0, 0);
        }
      } else {
        sacc[nt] = {-1e30f, -1e30f, -1e30f, -1e30f};
      }
    }
    if (kbase + 31 > q0) {  // causal mask (log2-domain scores)
#pragma unroll
      for (int nt = 0; nt < 2; nt++)
        if (nt < ntmax)
#pragma unroll
          for (int r = 0; r < 4; r++)
            if (kbase + nt * 16 + lr > q0 + lq * 4 + r) sacc[nt][r] = -1e30f;
    }
    float mt[4], alpha[4], rs[4];
#pragma unroll
    for (int r = 0; r < 4; r++) mt[r] = fmaxf(sacc[0][r], sacc[1][r]);
#pragma unroll
    for (int m = 1; m < 16; m <<= 1)
#pragma unroll
      for (int r = 0; r < 4; r++) mt[r] = fmaxf(mt[r], __shfl_xor(mt[r], m, 64));
#pragma unroll
    for (int r = 0; r < 4; r++) {
      float mn = fmaxf(m_i[r], mt[r]);
      alpha[r] = exp2f(m_i[r] - mn);
      m_i[r] = mn;
    }
#pragma unroll
    for (int nt = 0; nt < 2; nt++)
#pragma unroll
      for (int r = 0; r < 4; r++) sacc[nt][r] = exp2f(sacc[nt][r] - m_i[r]);
#pragma unroll
    for (int r = 0; r < 4; r++) rs[r] = sacc[0][r] + sacc[1][r];
#pragma unroll
    for (int m = 1; m < 16; m <<= 1)
#pragma unroll
      for (int r = 0; r < 4; r++) rs[r] += __shfl_xor(rs[r], m, 64);
#pragma unroll
    for (int r = 0; r < 4; r++) l_i[r] = l_i[r] * alpha[r] + rs[r];
#pragma unroll
    for (int f = 0; f < 16; f++) {
      o[f][0] *= alpha[0]; o[f][1] *= alpha[1];
      o[f][2] *= alpha[2]; o[f][3] *= alpha[3];
    }
    // P: C-layout -> LDS -> A-layout (per-wave buffer, no barrier needed)
    ushort_t* psw = Ps[wave];
#pragma unroll
    for (int nt = 0; nt < 2; nt++)
#pragma unroll
      for (int r = 0; r < 4; r++)
        psw[(lq * 4 + r) * 40 + nt * 16 + lr] = f2b(sacc[nt][r]);
    bf16x8 pf = *(const bf16x8*)&psw[lr * 40 + lq * 8];
#pragma unroll
    for (int f = 0; f < 16; f++) {
      bf16x8 vf = *(const bf16x8*)&Vs[f * 512 + lane * 8];
      o[f] = __builtin_amdgcn_mfma_f32_16x16x32_bf16(pf, vf, o[f], 0, 0, 0);
    }
  }
  float invl[4];
#pragma unroll
  for (int r = 0; r < 4; r++) invl[r] = 1.0f / l_i[r];
#pragma unroll
  for (int f = 0; f < 16; f++)
#pragma unroll
    for (int r = 0; r < 4; r++)
      O[((size_t)(b * S + q0 + lq * 4 + r) * H + h) * HD + f * 16 + lr] =
          f2b(o[f][r] * invl[r]);
}

// ---------------------------------------------------------------- launch
extern "C" void kernel_launch(void* const* d_in, const int* in_sizes, int n_in,
                              void* d_out, int out_size, void* d_ws, size_t ws_size,
                              hipStream_t stream) {
  const float* hs = (const float*)d_in[0];
  const float* Wq = (const float*)d_in[1];
  const float* Wk = (const float*)d_in[2];
  const float* Wv = (const float*)d_in[3];
  const float* Wo = (const float*)d_in[4];
  const float* qw = (const float*)d_in[5];
  const float* kw = (const float*)d_in[6];
  const int* pos = (const int*)d_in[7];
  float* out = (float*)d_out;

  char* ws = (char*)d_ws;
  size_t off = 0;
  auto alloc = [&](size_t bytes) {
    void* p = ws + off;
    off += (bytes + 255) & ~(size_t)255;
    return p;
  };
  ushort_t* Xb   = (ushort_t*)alloc((size_t)B * S * D * 2);
  ushort_t* Wqt  = (ushort_t*)alloc((size_t)(H * HD) * D * 2);
  ushort_t* Wkvt = (ushort_t*)alloc((size_t)(2 * KVH * HD) * D * 2);  // K rows then V rows
  ushort_t* Wot  = (ushort_t*)alloc((size_t)D * (H * HD) * 2);
  ushort_t* Qb   = (ushort_t*)alloc((size_t)B * S * H * HD * 2);
  ushort_t* Kb   = (ushort_t*)alloc((size_t)B * S * KVH * HD * 2);
  ushort_t* Vt   = (ushort_t*)alloc((size_t)B * KVH * HD * S * 2);
  ushort_t* Ab   = (ushort_t*)alloc((size_t)B * S * H * HD * 2);
  float*    tab  = (float*)alloc((size_t)S * 128 * 2 * sizeof(float));

  k_cvt_bf16<<<(B * S * D / 4 + 255) / 256, 256, 0, stream>>>(hs, Xb, B * S * D);
  k_transpose_cvt<<<dim3((H * HD) / 32, D / 32), dim3(32, 8), 0, stream>>>(Wq, Wqt, D, H * HD);
  k_transpose_cvt<<<dim3((KVH * HD) / 32, D / 32), dim3(32, 8), 0, stream>>>(Wk, Wkvt, D, KVH * HD);
  k_transpose_cvt<<<dim3((KVH * HD) / 32, D / 32), dim3(32, 8), 0, stream>>>(
      Wv, Wkvt + (size_t)(KVH * HD) * D, D, KVH * HD);
  k_transpose_cvt<<<dim3(D / 32, (H * HD) / 32), dim3(32, 8), 0, stream>>>(Wo, Wot, H * HD, D);
  k_rope_table<<<S * 128 / 256, 256, 0, stream>>>(pos, tab);

  k_gemm_bt<0><<<dim3(B * S / 128, (H * HD) / 128), 256, 0, stream>>>(
      Xb, Wqt, Qb, nullptr, B * S, H * HD, D);
  k_gemm_bt<3><<<dim3(B * S / 128, (2 * KVH * HD) / 128), 256, 0, stream>>>(
      Xb, Wkvt, Kb, Vt, B * S, 2 * KVH * HD, D);

  // Q scale folds 1/sqrt(HD)=1/16 AND log2(e) (softmax done in exp2 domain)
  k_norm_rope<<<B * S * H / 4, 256, 0, stream>>>(Qb, qw, tab, H, 0.0625f * 1.4426950408889634f);
  k_norm_rope<<<B * S * KVH / 4, 256, 0, stream>>>(Kb, kw, tab, KVH, 1.0f);

  k_attn<<<dim3(S / 64, H, B), 256, 0, stream>>>(Qb, Kb, Vt, Ab);

  k_gemm_bt<1><<<dim3(B * S / 128, D / 128), 256, 0, stream>>>(
      Ab, Wot, out, nullptr, B * S, D, H * HD);
}

// Round 4
// 702.046 us; speedup vs baseline: 1.7817x; 1.3427x over previous
//
#include <hip/hip_runtime.h>

typedef unsigned short ushort_t;
typedef __bf16 bf16_t;
typedef bf16_t bf16x8 __attribute__((ext_vector_type(8)));
typedef float floatx4 __attribute__((ext_vector_type(4)));
typedef ushort_t ushort4v __attribute__((ext_vector_type(4)));
typedef ushort_t ushort8v __attribute__((ext_vector_type(8)));

static constexpr int B = 2, S = 2048, D = 2048;
static constexpr int H = 16, KVH = 4, HD = 256;

#define DEVFN static __device__ __forceinline__

DEVFN ushort_t f2b(float f) {
  union { float f; unsigned u; } x; x.f = f;
  unsigned r = x.u + 0x7fffu + ((x.u >> 16) & 1u);
  return (ushort_t)(r >> 16);
}
DEVFN float b2f(ushort_t h) {
  union { unsigned u; float f; } x; x.u = ((unsigned)h) << 16;
  return x.f;
}
DEVFN void gll16(const void* g, void* l) {
  __builtin_amdgcn_global_load_lds(
      (const __attribute__((address_space(1))) void*)g,
      (__attribute__((address_space(3))) void*)l, 16, 0, 0);
}

// norm + rope one 256-elem row held as 4 elems/lane across a full wave.
// returns bf16x4 output for this lane.
DEVFN ushort4v norm_rope_row(ushort4v raw, const float* __restrict__ w,
                             const float* __restrict__ tab, int s, float scale, int lane) {
  float v[4];
  float ss = 0.f;
#pragma unroll
  for (int i = 0; i < 4; i++) { v[i] = b2f(raw[i]); ss += v[i] * v[i]; }
#pragma unroll
  for (int m = 1; m < 64; m <<= 1) ss += __shfl_xor(ss, m, 64);
  const float inv = rsqrtf(ss * (1.0f / HD) + 1e-6f);
  float4 wv = *(const float4*)(w + lane * 4);
  float y[4];
  y[0] = v[0] * inv * (1.0f + wv.x);
  y[1] = v[1] * inv * (1.0f + wv.y);
  y[2] = v[2] * inv * (1.0f + wv.z);
  y[3] = v[3] * inv * (1.0f + wv.w);
  float py[4];
#pragma unroll
  for (int i = 0; i < 4; i++) py[i] = __shfl_xor(y[i], 32, 64);
  const bool lo = (lane < 32);
  ushort4v ov;
#pragma unroll
  for (int i = 0; i < 4; i++) {
    int dd = (lane * 4 + i) & 127;
    float2 cs = *(const float2*)(tab + ((size_t)s * 128 + dd) * 2);
    float rot = lo ? -py[i] : py[i];
    ov[i] = f2b((y[i] * cs.x + rot * cs.y) * scale);
  }
  return ov;
}

// ---------------------------------------------------------------- conversions
__global__ void k_cvt_bf16(const float* __restrict__ in, ushort_t* __restrict__ out, int n) {
  int i = (blockIdx.x * 256 + threadIdx.x) * 4;
  if (i >= n) return;
  float4 v = *(const float4*)(in + i);
  ushort4v o;
  o[0] = f2b(v.x); o[1] = f2b(v.y); o[2] = f2b(v.z); o[3] = f2b(v.w);
  *(ushort4v*)(out + i) = o;
}

// in: R x C fp32 row-major; out: C x R bf16 row-major (out[c][r] = in[r][c])
__global__ void k_transpose_cvt(const float* __restrict__ in, ushort_t* __restrict__ out,
                                int R, int C) {
  __shared__ float tile[32][33];
  const int bx = blockIdx.x * 32, by = blockIdx.y * 32;
  const int tx = threadIdx.x, ty = threadIdx.y;
#pragma unroll
  for (int i = 0; i < 32; i += 8)
    tile[ty + i][tx] = in[(size_t)(by + ty + i) * C + bx + tx];
  __syncthreads();
#pragma unroll
  for (int i = 0; i < 32; i += 8)
    out[(size_t)(bx + ty + i) * R + by + tx] = f2b(tile[tx][ty + i]);
}

// cos/sin table: tab[(s*128+dd)*2] = cos, +1 = sin
__global__ void k_rope_table(const int* __restrict__ pos_ids, float* __restrict__ tab) {
  int idx = blockIdx.x * 256 + threadIdx.x;  // S*128 total
  int s = idx >> 7, dd = idx & 127;
  float ang = (float)pos_ids[s] * exp2f((float)dd * (-13.287712379549449f / 128.0f));
  tab[idx * 2] = cosf(ang);
  tab[idx * 2 + 1] = sinf(ang);
}

// ---------------------------------------------------------------- GEMM (A row-major MxK, Bt row-major NxK)
// MODE 0: bf16 row-major to C0. MODE 1: fp32 row-major to C0.
// MODE 3: fused KV — cols [0,1024) -> K bf16 row-major (ld 1024) to C0;
//   cols [1024,2048) -> V into MFMA-fragment-chunk layout in C1:
//   C1[((b*KVH+kvh)*(S/32)+tile)*8192 + f*512 + (lqv*16+lrv)*8 + j]
//     = V[b][s=tile*32+lqv*8+j][kvh][hd=f*16+lrv]
template <int MODE>
__global__ __launch_bounds__(256, 2)
void k_gemm_bt(const ushort_t* __restrict__ A, const ushort_t* __restrict__ Bt,
               void* __restrict__ C0, void* __restrict__ C1, int M, int N, int K) {
  __shared__ ushort_t As[128 * 32];
  __shared__ ushort_t Bs[128 * 32];
  const int lane = threadIdx.x & 63;
  const int wave = threadIdx.x >> 6;
  const int lr = lane & 15, lq = lane >> 4;
  const size_t m0 = (size_t)blockIdx.x * 128;
  const size_t n0 = (size_t)blockIdx.y * 128;
  const int wm = (wave & 1) * 4;
  const int wn = (wave >> 1) * 4;

  floatx4 acc[4][4];
#pragma unroll
  for (int i = 0; i < 4; i++)
#pragma unroll
    for (int j = 0; j < 4; j++) acc[i][j] = {0.f, 0.f, 0.f, 0.f};

  for (int kt = 0; kt < K; kt += 32) {
    __syncthreads();
#pragma unroll
    for (int i = 0; i < 2; i++) {
      const int c = wave * 2 + i;
      gll16(A + (m0 + c * 16 + lr) * K + kt + lq * 8, &As[c * 512 + lane * 8]);
      gll16(Bt + (n0 + c * 16 + lr) * K + kt + lq * 8, &Bs[c * 512 + lane * 8]);
    }
    __syncthreads();
    bf16x8 af[4], bfv[4];
#pragma unroll
    for (int i = 0; i < 4; i++) af[i] = *(const bf16x8*)&As[(wm + i) * 512 + lane * 8];
#pragma unroll
    for (int j = 0; j < 4; j++) bfv[j] = *(const bf16x8*)&Bs[(wn + j) * 512 + lane * 8];
#pragma unroll
    for (int i = 0; i < 4; i++)
#pragma unroll
      for (int j = 0; j < 4; j++)
        acc[i][j] = __builtin_amdgcn_mfma_f32_16x16x32_bf16(af[i], bfv[j], acc[i][j], 0, 0, 0);
  }

#pragma unroll
  for (int i = 0; i < 4; i++)
#pragma unroll
    for (int j = 0; j < 4; j++) {
      const size_t row0 = m0 + (size_t)(wm + i) * 16 + lq * 4;
      const size_t col = n0 + (size_t)(wn + j) * 16 + lr;
      if (MODE == 0) {
#pragma unroll
        for (int r = 0; r < 4; r++)
          ((ushort_t*)C0)[(row0 + r) * N + col] = f2b(acc[i][j][r]);
      } else if (MODE == 1) {
#pragma unroll
        for (int r = 0; r < 4; r++)
          ((float*)C0)[(row0 + r) * N + col] = acc[i][j][r];
      } else {  // MODE 3
        if (col < 1024) {
#pragma unroll
          for (int r = 0; r < 4; r++)
            ((ushort_t*)C0)[(row0 + r) * 1024 + col] = f2b(acc[i][j][r]);
        } else {
          const int ch = (int)col - 1024;
          const int kvh = ch >> 8, chh = ch & 255, f = chh >> 4, lrv = chh & 15;
          const size_t bb = row0 >> 11;
          const int s0 = (int)(row0 & 2047);
          const int tile = s0 >> 5, sl = s0 & 31, lqv = sl >> 3, j0 = sl & 7;
          ushort4v pk;
#pragma unroll
          for (int r = 0; r < 4; r++) pk[r] = f2b(acc[i][j][r]);
          *(ushort4v*)&((ushort_t*)C1)[((bb * KVH + kvh) * (S / 32) + tile) * 8192 +
                                       (size_t)(f * 64 + lqv * 16 + lrv) * 8 + j0] = pk;
        }
      }
    }
}

// ---------------------------------------------------------------- RMSNorm + RoPE, row-major in-place (Q)
__global__ void k_norm_rope(ushort_t* __restrict__ x, const float* __restrict__ w,
                            const float* __restrict__ tab, int heads, float scale) {
  const int lane = threadIdx.x & 63;
  const size_t row = (size_t)blockIdx.x * 4 + (threadIdx.x >> 6);
  const int s = (int)((row / heads) % S);
  ushort_t* p = x + row * HD + lane * 4;
  ushort4v raw = *(const ushort4v*)p;
  *(ushort4v*)p = norm_rope_row(raw, w, tab, s, scale, lane);
}

// ---------------------------------------------------------------- RMSNorm + RoPE + swizzle (K)
// grid (S/32, KVH, B); reads Kb row-major [b][s][kvh][hd], writes Kf in
// MFMA chunk order: Kf[((b*KVH+kvh)*(S/32)+tile)*8192 + c*512 + lane*8 + j]
//   = K[s=tile*32+nt*16+lr][hd=ks*32+lq*8+j],  c=nt*8+ks
__global__ void k_norm_rope_k(const ushort_t* __restrict__ Kb, ushort_t* __restrict__ Kf,
                              const float* __restrict__ w, const float* __restrict__ tab) {
  __shared__ ushort_t t[32 * 264];  // rows padded +8 to break bank alias
  const int lane = threadIdx.x & 63, wave = threadIdx.x >> 6;
  const int tile = blockIdx.x, kvh = blockIdx.y, b = blockIdx.z;
#pragma unroll
  for (int rr = 0; rr < 8; rr++) {
    const int row = wave * 8 + rr;
    const int s = tile * 32 + row;
    const ushort_t* p = Kb + ((size_t)(b * S + s) * KVH + kvh) * HD + lane * 4;
    ushort4v raw = *(const ushort4v*)p;
    *(ushort4v*)&t[row * 264 + lane * 4] = norm_rope_row(raw, w, tab, s, 1.0f, lane);
  }
  __syncthreads();
  ushort_t* dst = Kf + ((size_t)(b * KVH + kvh) * (S / 32) + tile) * 8192;
  const int lr = lane & 15, lq = lane >> 4;
#pragma unroll
  for (int q = 0; q < 4; q++) {
    const int c = q * 4 + wave;           // chunk, wave-uniform
    const int nt = c >> 3, ks = c & 7;
    ushort8v v = *(const ushort8v*)&t[(nt * 16 + lr) * 264 + ks * 32 + lq * 8];
    *(ushort8v*)&dst[(size_t)c * 512 + lane * 8] = v;
  }
}

// ---------------------------------------------------------------- flash attention
// grid (S/128, H, B); block 256 = 4 waves x 16 q-rows; kv-tile 32.
// Block p processes q-tiles {S/64-1-p, p} -> constant 66 kv-tiles/block (no tail).
// K and V arrive in fragment-chunk global layout -> every gll16 is a
// contiguous 1024B transaction.
// launch_bounds(256,3): (256,4) capped VGPR at 128 and spilled (r2).
__global__ __launch_bounds__(256, 3)
void k_attn(const ushort_t* __restrict__ Q, const ushort_t* __restrict__ Kf,
            const ushort_t* __restrict__ Vf, ushort_t* __restrict__ O) {
  __shared__ ushort_t Ks[16 * 512];   // chunks c = nt*8+ks
  __shared__ ushort_t Vs[16 * 512];   // chunks f = hd-tile
  __shared__ ushort_t Ps[4][16 * 40]; // per-wave P, row stride 40
  const int lane = threadIdx.x & 63, wave = threadIdx.x >> 6;
  const int lr = lane & 15, lq = lane >> 4;
  const int h = blockIdx.y, b = blockIdx.z;
  const int kvh = h >> 2;
  const size_t kvb = (size_t)(b * KVH + kvh) * (S / 32);

#pragma unroll 1
  for (int half = 0; half < 2; half++) {
    const int qt = half ? (int)blockIdx.x : (S / 64 - 1 - (int)blockIdx.x);
    const int q0 = qt * 64 + wave * 16;

    bf16x8 qf[8];
    {
      const ushort_t* qp = Q + ((size_t)(b * S + q0 + lr) * H + h) * HD + lq * 8;
#pragma unroll
      for (int ks = 0; ks < 8; ks++) qf[ks] = *(const bf16x8*)(qp + ks * 32);
    }
    floatx4 o[16];
#pragma unroll
    for (int f = 0; f < 16; f++) o[f] = {0.f, 0.f, 0.f, 0.f};
    float m_i[4] = {-1e30f, -1e30f, -1e30f, -1e30f};
    float l_i[4] = {0.f, 0.f, 0.f, 0.f};

    const int ntiles = (qt + 1) * 2;
    for (int kt = 0; kt < ntiles; kt++) {
      const int kbase = kt * 32;
      __syncthreads();  // previous tile's LDS reads done
      const ushort_t* tb = Kf + (kvb + kt) * 8192;   // K chunks
      const ushort_t* vb = Vf + (kvb + kt) * 8192;   // V chunks
#pragma unroll
      for (int i = 0; i < 4; i++) {
        const int c = wave * 4 + i;
        if (c < 16) gll16(tb + (size_t)c * 512 + lane * 8, &Ks[c * 512 + lane * 8]);
        else {
          const int f = c - 16;
          gll16(vb + (size_t)f * 512 + lane * 8, &Vs[f * 512 + lane * 8]);
        }
      }
#pragma unroll
      for (int i = 0; i < 4; i++) {
        const int c = wave * 4 + i + (wave < 2 ? 16 : -16) * 0;  // second half
        const int c2 = wave * 4 + i + 16;
        if (c2 < 32) {
          if (c2 < 16) gll16(tb + (size_t)c2 * 512 + lane * 8, &Ks[c2 * 512 + lane * 8]);
          else {
            const int f = c2 - 16;
            gll16(vb + (size_t)f * 512 + lane * 8, &Vs[f * 512 + lane * 8]);
          }
        }
      }
      __syncthreads();  // staging drained
      if (kbase > q0 + 15) continue;
      const int ntmax = min(2, ((q0 + 15 - kbase) >> 4) + 1);

      floatx4 sacc[2];
#pragma unroll
      for (int nt = 0; nt < 2; nt++) {
        if (nt < ntmax) {
          sacc[nt] = {0.f, 0.f, 0.f, 0.f};
#pragma unroll
          for (int ks = 0; ks < 8; ks++) {
            bf16x8 kf = *(const bf16x8*)&Ks[(nt * 8 + ks) * 512 + lane * 8];
            sacc[nt] = __builtin_amdgcn_mfma_f32_16x16x32_bf16(qf[ks], kf, sacc[nt], 0, 0, 0);
          }
        } else {
          sacc[nt] = {-1e30f, -1e30f, -1e30f, -1e30f};
        }
      }
      if (kbase + 31 > q0) {  // causal mask
#pragma unroll
        for (int nt = 0; nt < 2; nt++)
          if (nt < ntmax)
#pragma unroll
            for (int r = 0; r < 4; r++)
              if (kbase + nt * 16 + lr > q0 + lq * 4 + r) sacc[nt][r] = -1e30f;
      }
      float mt[4], alpha[4], rs[4];
#pragma unroll
      for (int r = 0; r < 4; r++) mt[r] = fmaxf(sacc[0][r], sacc[1][r]);
#pragma unroll
      for (int m = 1; m < 16; m <<= 1)
#pragma unroll
        for (int r = 0; r < 4; r++) mt[r] = fmaxf(mt[r], __shfl_xor(mt[r], m, 64));
#pragma unroll
      for (int r = 0; r < 4; r++) {
        float mn = fmaxf(m_i[r], mt[r]);
        alpha[r] = exp2f(m_i[r] - mn);
        m_i[r] = mn;
      }
#pragma unroll
      for (int nt = 0; nt < 2; nt++)
#pragma unroll
        for (int r = 0; r < 4; r++) sacc[nt][r] = exp2f(sacc[nt][r] - m_i[r]);
#pragma unroll
      for (int r = 0; r < 4; r++) rs[r] = sacc[0][r] + sacc[1][r];
#pragma unroll
      for (int m = 1; m < 16; m <<= 1)
#pragma unroll
        for (int r = 0; r < 4; r++) rs[r] += __shfl_xor(rs[r], m, 64);
#pragma unroll
      for (int r = 0; r < 4; r++) l_i[r] = l_i[r] * alpha[r] + rs[r];
#pragma unroll
      for (int f = 0; f < 16; f++) {
        o[f][0] *= alpha[0]; o[f][1] *= alpha[1];
        o[f][2] *= alpha[2]; o[f][3] *= alpha[3];
      }
      ushort_t* psw = Ps[wave];
#pragma unroll
      for (int nt = 0; nt < 2; nt++)
#pragma unroll
        for (int r = 0; r < 4; r++)
          psw[(lq * 4 + r) * 40 + nt * 16 + lr] = f2b(sacc[nt][r]);
      bf16x8 pf = *(const bf16x8*)&psw[lr * 40 + lq * 8];
#pragma unroll
      for (int f = 0; f < 16; f++) {
        bf16x8 vf = *(const bf16x8*)&Vs[f * 512 + lane * 8];
        o[f] = __builtin_amdgcn_mfma_f32_16x16x32_bf16(pf, vf, o[f], 0, 0, 0);
      }
    }
    float invl[4];
#pragma unroll
    for (int r = 0; r < 4; r++) invl[r] = 1.0f / l_i[r];
#pragma unroll
    for (int f = 0; f < 16; f++)
#pragma unroll
      for (int r = 0; r < 4; r++)
        O[((size_t)(b * S + q0 + lq * 4 + r) * H + h) * HD + f * 16 + lr] =
            f2b(o[f][r] * invl[r]);
  }
}

// ---------------------------------------------------------------- launch
extern "C" void kernel_launch(void* const* d_in, const int* in_sizes, int n_in,
                              void* d_out, int out_size, void* d_ws, size_t ws_size,
                              hipStream_t stream) {
  const float* hs = (const float*)d_in[0];
  const float* Wq = (const float*)d_in[1];
  const float* Wk = (const float*)d_in[2];
  const float* Wv = (const float*)d_in[3];
  const float* Wo = (const float*)d_in[4];
  const float* qw = (const float*)d_in[5];
  const float* kw = (const float*)d_in[6];
  const int* pos = (const int*)d_in[7];
  float* out = (float*)d_out;

  char* ws = (char*)d_ws;
  size_t off = 0;
  auto alloc = [&](size_t bytes) {
    void* p = ws + off;
    off += (bytes + 255) & ~(size_t)255;
    return p;
  };
  ushort_t* Xb   = (ushort_t*)alloc((size_t)B * S * D * 2);
  ushort_t* Wqt  = (ushort_t*)alloc((size_t)(H * HD) * D * 2);
  ushort_t* Wkvt = (ushort_t*)alloc((size_t)(2 * KVH * HD) * D * 2);  // K rows then V rows
  ushort_t* Wot  = (ushort_t*)alloc((size_t)D * (H * HD) * 2);
  ushort_t* Qb   = (ushort_t*)alloc((size_t)B * S * H * HD * 2);
  ushort_t* Kf   = (ushort_t*)alloc((size_t)B * S * KVH * HD * 2);  // swizzled K
  ushort_t* Vf   = (ushort_t*)alloc((size_t)B * S * KVH * HD * 2);  // swizzled V
  ushort_t* Ab   = (ushort_t*)alloc((size_t)B * S * H * HD * 2);
  float*    tab  = (float*)alloc((size_t)S * 128 * 2 * sizeof(float));
  // Kb (row-major K pre-norm) aliases Ab: consumed by k_norm_rope_k before k_attn writes Ab
  ushort_t* Kb = Ab;

  k_cvt_bf16<<<(B * S * D / 4 + 255) / 256, 256, 0, stream>>>(hs, Xb, B * S * D);
  k_transpose_cvt<<<dim3((H * HD) / 32, D / 32), dim3(32, 8), 0, stream>>>(Wq, Wqt, D, H * HD);
  k_transpose_cvt<<<dim3((KVH * HD) / 32, D / 32), dim3(32, 8), 0, stream>>>(Wk, Wkvt, D, KVH * HD);
  k_transpose_cvt<<<dim3((KVH * HD) / 32, D / 32), dim3(32, 8), 0, stream>>>(
      Wv, Wkvt + (size_t)(KVH * HD) * D, D, KVH * HD);
  k_transpose_cvt<<<dim3(D / 32, (H * HD) / 32), dim3(32, 8), 0, stream>>>(Wo, Wot, H * HD, D);
  k_rope_table<<<S * 128 / 256, 256, 0, stream>>>(pos, tab);

  k_gemm_bt<0><<<dim3(B * S / 128, (H * HD) / 128), 256, 0, stream>>>(
      Xb, Wqt, Qb, nullptr, B * S, H * HD, D);
  k_gemm_bt<3><<<dim3(B * S / 128, (2 * KVH * HD) / 128), 256, 0, stream>>>(
      Xb, Wkvt, Kb, Vf, B * S, 2 * KVH * HD, D);

  // Q scale folds 1/sqrt(HD)=1/16 AND log2(e) (softmax in exp2 domain)
  k_norm_rope<<<B * S * H / 4, 256, 0, stream>>>(Qb, qw, tab, H, 0.0625f * 1.4426950408889634f);
  k_norm_rope_k<<<dim3(S / 32, KVH, B), 256, 0, stream>>>(Kb, Kf, kw, tab);

  k_attn<<<dim3(S / 128, H, B), 256, 0, stream>>>(Qb, Kf, Vf, Ab);

  k_gemm_bt<1><<<dim3(B * S / 128, D / 128), 256, 0, stream>>>(
      Ab, Wot, out, nullptr, B * S, D, H * HD);
}

// Round 5
// 644.085 us; speedup vs baseline: 1.9421x; 1.0900x over previous
//
#include <hip/hip_runtime.h>

typedef unsigned short ushort_t;
typedef __bf16 bf16_t;
typedef bf16_t bf16x8 __attribute__((ext_vector_type(8)));
typedef float floatx4 __attribute__((ext_vector_type(4)));
typedef ushort_t ushort4v __attribute__((ext_vector_type(4)));
typedef ushort_t ushort8v __attribute__((ext_vector_type(8)));

static constexpr int B = 2, S = 2048, D = 2048;
static constexpr int H = 16, KVH = 4, HD = 256;

#define DEVFN static __device__ __forceinline__

DEVFN ushort_t f2b(float f) {
  union { float f; unsigned u; } x; x.f = f;
  unsigned r = x.u + 0x7fffu + ((x.u >> 16) & 1u);
  return (ushort_t)(r >> 16);
}
DEVFN float b2f(ushort_t h) {
  union { unsigned u; float f; } x; x.u = ((unsigned)h) << 16;
  return x.f;
}
DEVFN void gll16(const void* g, void* l) {
  __builtin_amdgcn_global_load_lds(
      (const __attribute__((address_space(1))) void*)g,
      (__attribute__((address_space(3))) void*)l, 16, 0, 0);
}

// norm + rope one 256-elem row held as 4 elems/lane across a full wave.
DEVFN ushort4v norm_rope_row(ushort4v raw, const float* __restrict__ w,
                             const float* __restrict__ tab, int s, float scale, int lane) {
  float v[4];
  float ss = 0.f;
#pragma unroll
  for (int i = 0; i < 4; i++) { v[i] = b2f(raw[i]); ss += v[i] * v[i]; }
#pragma unroll
  for (int m = 1; m < 64; m <<= 1) ss += __shfl_xor(ss, m, 64);
  const float inv = rsqrtf(ss * (1.0f / HD) + 1e-6f);
  float4 wv = *(const float4*)(w + lane * 4);
  float y[4];
  y[0] = v[0] * inv * (1.0f + wv.x);
  y[1] = v[1] * inv * (1.0f + wv.y);
  y[2] = v[2] * inv * (1.0f + wv.z);
  y[3] = v[3] * inv * (1.0f + wv.w);
  float py[4];
#pragma unroll
  for (int i = 0; i < 4; i++) py[i] = __shfl_xor(y[i], 32, 64);
  const bool lo = (lane < 32);
  ushort4v ov;
#pragma unroll
  for (int i = 0; i < 4; i++) {
    int dd = (lane * 4 + i) & 127;
    float2 cs = *(const float2*)(tab + ((size_t)s * 128 + dd) * 2);
    float rot = lo ? -py[i] : py[i];
    ov[i] = f2b((y[i] * cs.x + rot * cs.y) * scale);
  }
  return ov;
}

// ---------------------------------------------------------------- conversions
__global__ void k_cvt_bf16(const float* __restrict__ in, ushort_t* __restrict__ out, int n) {
  int i = (blockIdx.x * 256 + threadIdx.x) * 4;
  if (i >= n) return;
  float4 v = *(const float4*)(in + i);
  ushort4v o;
  o[0] = f2b(v.x); o[1] = f2b(v.y); o[2] = f2b(v.z); o[3] = f2b(v.w);
  *(ushort4v*)(out + i) = o;
}

// in: R x C fp32 row-major; out: C x R bf16 row-major. 64x64 tiles:
// float4 reads (256B/group), ushort4 writes (128B/group), pad-65 LDS (2-way, free).
__global__ void k_transpose_cvt(const float* __restrict__ in, ushort_t* __restrict__ out,
                                int R, int C) {
  __shared__ float tile[64][65];
  const int cb = blockIdx.x * 64, rb = blockIdx.y * 64;
  const int t = threadIdx.x;
  const int l16 = t & 15, g16 = t >> 4;
#pragma unroll
  for (int p = 0; p < 4; p++) {
    const int r = p * 16 + g16;
    float4 v = *(const float4*)(in + (size_t)(rb + r) * C + cb + l16 * 4);
    tile[r][l16 * 4 + 0] = v.x;
    tile[r][l16 * 4 + 1] = v.y;
    tile[r][l16 * 4 + 2] = v.z;
    tile[r][l16 * 4 + 3] = v.w;
  }
  __syncthreads();
#pragma unroll
  for (int p = 0; p < 4; p++) {
    const int c = p * 16 + g16;
    ushort4v o4;
#pragma unroll
    for (int i = 0; i < 4; i++) o4[i] = f2b(tile[l16 * 4 + i][c]);
    *(ushort4v*)(out + (size_t)(cb + c) * R + rb + l16 * 4) = o4;
  }
}

// cos/sin table: tab[(s*128+dd)*2] = cos, +1 = sin
__global__ void k_rope_table(const int* __restrict__ pos_ids, float* __restrict__ tab) {
  int idx = blockIdx.x * 256 + threadIdx.x;  // S*128 total
  int s = idx >> 7, dd = idx & 127;
  float ang = (float)pos_ids[s] * exp2f((float)dd * (-13.287712379549449f / 128.0f));
  tab[idx * 2] = cosf(ang);
  tab[idx * 2 + 1] = sinf(ang);
}

// ---------------------------------------------------------------- GEMM (A row-major MxK, Bt row-major NxK)
// MODE 0: bf16 row-major to C0. MODE 1: fp32 row-major to C0.
// MODE 3: fused KV — cols [0,1024) -> K bf16 row-major (ld 1024) to C0;
//   cols [1024,2048) -> V into 64-row MFMA-fragment-chunk layout in C1:
//   C1[((b*KVH+kvh)*(S/64)+tile)*16384 + (f*2+kh)*512 + (lqv*16+lrv)*8 + j]
//     = V[b][s=tile*64+kh*32+lqv*8+j][kvh][hd=f*16+lrv]
template <int MODE>
__global__ __launch_bounds__(256, 2)
void k_gemm_bt(const ushort_t* __restrict__ A, const ushort_t* __restrict__ Bt,
               void* __restrict__ C0, void* __restrict__ C1, int M, int N, int K) {
  __shared__ ushort_t As[128 * 32];
  __shared__ ushort_t Bs[128 * 32];
  const int lane = threadIdx.x & 63;
  const int wave = threadIdx.x >> 6;
  const int lr = lane & 15, lq = lane >> 4;
  const size_t m0 = (size_t)blockIdx.x * 128;
  const size_t n0 = (size_t)blockIdx.y * 128;
  const int wm = (wave & 1) * 4;
  const int wn = (wave >> 1) * 4;

  floatx4 acc[4][4];
#pragma unroll
  for (int i = 0; i < 4; i++)
#pragma unroll
    for (int j = 0; j < 4; j++) acc[i][j] = {0.f, 0.f, 0.f, 0.f};

  for (int kt = 0; kt < K; kt += 32) {
    __syncthreads();
#pragma unroll
    for (int i = 0; i < 2; i++) {
      const int c = wave * 2 + i;
      gll16(A + (m0 + c * 16 + lr) * K + kt + lq * 8, &As[c * 512 + lane * 8]);
      gll16(Bt + (n0 + c * 16 + lr) * K + kt + lq * 8, &Bs[c * 512 + lane * 8]);
    }
    __syncthreads();
    bf16x8 af[4], bfv[4];
#pragma unroll
    for (int i = 0; i < 4; i++) af[i] = *(const bf16x8*)&As[(wm + i) * 512 + lane * 8];
#pragma unroll
    for (int j = 0; j < 4; j++) bfv[j] = *(const bf16x8*)&Bs[(wn + j) * 512 + lane * 8];
#pragma unroll
    for (int i = 0; i < 4; i++)
#pragma unroll
      for (int j = 0; j < 4; j++)
        acc[i][j] = __builtin_amdgcn_mfma_f32_16x16x32_bf16(af[i], bfv[j], acc[i][j], 0, 0, 0);
  }

#pragma unroll
  for (int i = 0; i < 4; i++)
#pragma unroll
    for (int j = 0; j < 4; j++) {
      const size_t row0 = m0 + (size_t)(wm + i) * 16 + lq * 4;
      const size_t col = n0 + (size_t)(wn + j) * 16 + lr;
      if (MODE == 0) {
#pragma unroll
        for (int r = 0; r < 4; r++)
          ((ushort_t*)C0)[(row0 + r) * N + col] = f2b(acc[i][j][r]);
      } else if (MODE == 1) {
#pragma unroll
        for (int r = 0; r < 4; r++)
          ((float*)C0)[(row0 + r) * N + col] = acc[i][j][r];
      } else {  // MODE 3
        if (col < 1024) {
#pragma unroll
          for (int r = 0; r < 4; r++)
            ((ushort_t*)C0)[(row0 + r) * 1024 + col] = f2b(acc[i][j][r]);
        } else {
          const int ch = (int)col - 1024;
          const int kvh = ch >> 8, chh = ch & 255, f = chh >> 4, lrv = chh & 15;
          const size_t bb = row0 >> 11;
          const int s0 = (int)(row0 & 2047);
          const int tile = s0 >> 6, kh = (s0 >> 5) & 1, lqv = (s0 >> 3) & 3, j0 = s0 & 7;
          ushort4v pk;
#pragma unroll
          for (int r = 0; r < 4; r++) pk[r] = f2b(acc[i][j][r]);
          *(ushort4v*)&((ushort_t*)C1)[((bb * KVH + kvh) * (S / 64) + tile) * 16384 +
                                       (size_t)(f * 2 + kh) * 512 +
                                       (size_t)(lqv * 16 + lrv) * 8 + j0] = pk;
        }
      }
    }
}

// ---------------------------------------------------------------- RMSNorm + RoPE, row-major in-place (Q)
__global__ void k_norm_rope(ushort_t* __restrict__ x, const float* __restrict__ w,
                            const float* __restrict__ tab, int heads, float scale) {
  const int lane = threadIdx.x & 63;
  const size_t row = (size_t)blockIdx.x * 4 + (threadIdx.x >> 6);
  const int s = (int)((row / heads) % S);
  ushort_t* p = x + row * HD + lane * 4;
  ushort4v raw = *(const ushort4v*)p;
  *(ushort4v*)p = norm_rope_row(raw, w, tab, s, scale, lane);
}

// ---------------------------------------------------------------- RMSNorm + RoPE + swizzle (K)
// grid (S/64, KVH, B); reads Kb row-major [b][s][kvh][hd], writes Kf in 64-row
// MFMA chunk order: Kf[((b*KVH+kvh)*(S/64)+tile)*16384 + c*512 + lane*8 + j]
//   = K[s=tile*64+nt*16+lr][hd=ks*32+lq*8+j],  c=nt*8+ks, nt 0..3
__global__ void k_norm_rope_k(const ushort_t* __restrict__ Kb, ushort_t* __restrict__ Kf,
                              const float* __restrict__ w, const float* __restrict__ tab) {
  __shared__ ushort_t t[64 * 264];  // rows padded +8
  const int lane = threadIdx.x & 63, wave = threadIdx.x >> 6;
  const int tile = blockIdx.x, kvh = blockIdx.y, b = blockIdx.z;
#pragma unroll
  for (int rr = 0; rr < 16; rr++) {
    const int row = wave * 16 + rr;
    const int s = tile * 64 + row;
    const ushort_t* p = Kb + ((size_t)(b * S + s) * KVH + kvh) * HD + lane * 4;
    ushort4v raw = *(const ushort4v*)p;
    *(ushort4v*)&t[row * 264 + lane * 4] = norm_rope_row(raw, w, tab, s, 1.0f, lane);
  }
  __syncthreads();
  ushort_t* dst = Kf + ((size_t)(b * KVH + kvh) * (S / 64) + tile) * 16384;
  const int lr = lane & 15, lq = lane >> 4;
#pragma unroll
  for (int q = 0; q < 8; q++) {
    const int c = wave * 8 + q;            // chunk, wave-uniform
    const int nt = c >> 3, ks = c & 7;
    ushort8v v = *(const ushort8v*)&t[(nt * 16 + lr) * 264 + ks * 32 + lq * 8];
    *(ushort8v*)&dst[(size_t)c * 512 + lane * 8] = v;
  }
}

// ---------------------------------------------------------------- flash attention
// grid (S/128, H, B); block 256 = 4 waves x 16 q-rows; kv-tile 64.
// Block p processes q-tiles {S/64-1-p, p} -> constant 33 kv-tiles/block.
// K and V in 64-row fragment-chunk global layout -> contiguous 1KB gll16.
// LDS 74.7KB -> 2 blocks/CU; launch_bounds(256,2): VGPR cap 256, no spill
// ((256,4) spilled in r2; kernel needs ~160 unified regs with kv=64).
__global__ __launch_bounds__(256, 2)
void k_attn(const ushort_t* __restrict__ Q, const ushort_t* __restrict__ Kf,
            const ushort_t* __restrict__ Vf, ushort_t* __restrict__ O) {
  __shared__ ushort_t Ks[32 * 512];   // chunks c = nt*8+ks, nt 0..3
  __shared__ ushort_t Vs[32 * 512];   // chunks (f*2+kh), f 0..15, kh 0..1
  __shared__ ushort_t Ps[4][16 * 72]; // per-wave P 16x64, row stride 72 (144B, 16B-mult)
  const int lane = threadIdx.x & 63, wave = threadIdx.x >> 6;
  const int lr = lane & 15, lq = lane >> 4;
  const int h = blockIdx.y, b = blockIdx.z;
  const int kvh = h >> 2;
  const size_t kvb = (size_t)(b * KVH + kvh) * (S / 64);

#pragma unroll 1
  for (int half = 0; half < 2; half++) {
    const int qt = half ? (int)blockIdx.x : (S / 64 - 1 - (int)blockIdx.x);
    const int q0 = qt * 64 + wave * 16;

    bf16x8 qf[8];
    {
      const ushort_t* qp = Q + ((size_t)(b * S + q0 + lr) * H + h) * HD + lq * 8;
#pragma unroll
      for (int ks = 0; ks < 8; ks++) qf[ks] = *(const bf16x8*)(qp + ks * 32);
    }
    floatx4 o[16];
#pragma unroll
    for (int f = 0; f < 16; f++) o[f] = {0.f, 0.f, 0.f, 0.f};
    float m_i[4] = {-1e30f, -1e30f, -1e30f, -1e30f};
    float l_i[4] = {0.f, 0.f, 0.f, 0.f};

    const int ntiles = qt + 1;
    for (int kt = 0; kt < ntiles; kt++) {
      const int kbase = kt * 64;
      __syncthreads();  // previous tile's LDS reads done
      const ushort_t* tb = Kf + (kvb + kt) * 16384;
      const ushort_t* vb = Vf + (kvb + kt) * 16384;
#pragma unroll
      for (int i = 0; i < 16; i++) {
        const int c = wave * 16 + i;
        if (c < 32) gll16(tb + (size_t)c * 512 + lane * 8, &Ks[c * 512 + lane * 8]);
        else        gll16(vb + (size_t)(c - 32) * 512 + lane * 8, &Vs[(c - 32) * 512 + lane * 8]);
      }
      __syncthreads();  // staging drained

      const int ntmax = min(4, ((q0 + 15 - kbase) >> 4) + 1);  // >= 1 always
      floatx4 sacc[4];
#pragma unroll
      for (int nt = 0; nt < 4; nt++) {
        if (nt < ntmax) {
          sacc[nt] = {0.f, 0.f, 0.f, 0.f};
#pragma unroll
          for (int ks = 0; ks < 8; ks++) {
            bf16x8 kf = *(const bf16x8*)&Ks[(nt * 8 + ks) * 512 + lane * 8];
            sacc[nt] = __builtin_amdgcn_mfma_f32_16x16x32_bf16(qf[ks], kf, sacc[nt], 0, 0, 0);
          }
        } else {
          sacc[nt] = {-1e30f, -1e30f, -1e30f, -1e30f};
        }
      }
      if (kbase + 63 > q0) {  // causal mask on diagonal tiles
#pragma unroll
        for (int nt = 0; nt < 4; nt++)
          if (nt < ntmax)
#pragma unroll
            for (int r = 0; r < 4; r++)
              if (kbase + nt * 16 + lr > q0 + lq * 4 + r) sacc[nt][r] = -1e30f;
      }
      float mt[4], alpha[4], rs[4];
#pragma unroll
      for (int r = 0; r < 4; r++)
        mt[r] = fmaxf(fmaxf(sacc[0][r], sacc[1][r]), fmaxf(sacc[2][r], sacc[3][r]));
#pragma unroll
      for (int m = 1; m < 16; m <<= 1)
#pragma unroll
        for (int r = 0; r < 4; r++) mt[r] = fmaxf(mt[r], __shfl_xor(mt[r], m, 64));
#pragma unroll
      for (int r = 0; r < 4; r++) {
        float mn = fmaxf(m_i[r], mt[r]);
        alpha[r] = exp2f(m_i[r] - mn);
        m_i[r] = mn;
      }
#pragma unroll
      for (int nt = 0; nt < 4; nt++)
#pragma unroll
        for (int r = 0; r < 4; r++) sacc[nt][r] = exp2f(sacc[nt][r] - m_i[r]);
#pragma unroll
      for (int r = 0; r < 4; r++)
        rs[r] = (sacc[0][r] + sacc[1][r]) + (sacc[2][r] + sacc[3][r]);
#pragma unroll
      for (int m = 1; m < 16; m <<= 1)
#pragma unroll
        for (int r = 0; r < 4; r++) rs[r] += __shfl_xor(rs[r], m, 64);
#pragma unroll
      for (int r = 0; r < 4; r++) l_i[r] = l_i[r] * alpha[r] + rs[r];
      // skip the 64-mul rescale when no row's max changed (common in steady state)
      if (__any((alpha[0] < 1.f) | (alpha[1] < 1.f) | (alpha[2] < 1.f) | (alpha[3] < 1.f))) {
#pragma unroll
        for (int f = 0; f < 16; f++) {
          o[f][0] *= alpha[0]; o[f][1] *= alpha[1];
          o[f][2] *= alpha[2]; o[f][3] *= alpha[3];
        }
      }
      ushort_t* psw = Ps[wave];
#pragma unroll
      for (int nt = 0; nt < 4; nt++)
#pragma unroll
        for (int r = 0; r < 4; r++)
          psw[(lq * 4 + r) * 72 + nt * 16 + lr] = f2b(sacc[nt][r]);
      bf16x8 pf0 = *(const bf16x8*)&psw[lr * 72 + lq * 8];
      bf16x8 pf1 = *(const bf16x8*)&psw[lr * 72 + 32 + lq * 8];
#pragma unroll
      for (int f = 0; f < 16; f++) {
        bf16x8 vf0 = *(const bf16x8*)&Vs[(f * 2 + 0) * 512 + lane * 8];
        o[f] = __builtin_amdgcn_mfma_f32_16x16x32_bf16(pf0, vf0, o[f], 0, 0, 0);
        bf16x8 vf1 = *(const bf16x8*)&Vs[(f * 2 + 1) * 512 + lane * 8];
        o[f] = __builtin_amdgcn_mfma_f32_16x16x32_bf16(pf1, vf1, o[f], 0, 0, 0);
      }
    }
    float invl[4];
#pragma unroll
    for (int r = 0; r < 4; r++) invl[r] = 1.0f / l_i[r];
#pragma unroll
    for (int f = 0; f < 16; f++)
#pragma unroll
      for (int r = 0; r < 4; r++)
        O[((size_t)(b * S + q0 + lq * 4 + r) * H + h) * HD + f * 16 + lr] =
            f2b(o[f][r] * invl[r]);
  }
}

// ---------------------------------------------------------------- launch
extern "C" void kernel_launch(void* const* d_in, const int* in_sizes, int n_in,
                              void* d_out, int out_size, void* d_ws, size_t ws_size,
                              hipStream_t stream) {
  const float* hs = (const float*)d_in[0];
  const float* Wq = (const float*)d_in[1];
  const float* Wk = (const float*)d_in[2];
  const float* Wv = (const float*)d_in[3];
  const float* Wo = (const float*)d_in[4];
  const float* qw = (const float*)d_in[5];
  const float* kw = (const float*)d_in[6];
  const int* pos = (const int*)d_in[7];
  float* out = (float*)d_out;

  char* ws = (char*)d_ws;
  size_t off = 0;
  auto alloc = [&](size_t bytes) {
    void* p = ws + off;
    off += (bytes + 255) & ~(size_t)255;
    return p;
  };
  ushort_t* Xb   = (ushort_t*)alloc((size_t)B * S * D * 2);
  ushort_t* Wqt  = (ushort_t*)alloc((size_t)(H * HD) * D * 2);
  ushort_t* Wkvt = (ushort_t*)alloc((size_t)(2 * KVH * HD) * D * 2);  // K rows then V rows
  ushort_t* Wot  = (ushort_t*)alloc((size_t)D * (H * HD) * 2);
  ushort_t* Qb   = (ushort_t*)alloc((size_t)B * S * H * HD * 2);
  ushort_t* Kf   = (ushort_t*)alloc((size_t)B * S * KVH * HD * 2);  // swizzled K (64-row tiles)
  ushort_t* Vf   = (ushort_t*)alloc((size_t)B * S * KVH * HD * 2);  // swizzled V (64-row tiles)
  ushort_t* Ab   = (ushort_t*)alloc((size_t)B * S * H * HD * 2);
  float*    tab  = (float*)alloc((size_t)S * 128 * 2 * sizeof(float));
  // Kb (row-major K pre-norm) aliases Ab: consumed by k_norm_rope_k before k_attn writes Ab
  ushort_t* Kb = Ab;

  k_cvt_bf16<<<(B * S * D / 4 + 255) / 256, 256, 0, stream>>>(hs, Xb, B * S * D);
  k_transpose_cvt<<<dim3((H * HD) / 64, D / 64), 256, 0, stream>>>(Wq, Wqt, D, H * HD);
  k_transpose_cvt<<<dim3((KVH * HD) / 64, D / 64), 256, 0, stream>>>(Wk, Wkvt, D, KVH * HD);
  k_transpose_cvt<<<dim3((KVH * HD) / 64, D / 64), 256, 0, stream>>>(
      Wv, Wkvt + (size_t)(KVH * HD) * D, D, KVH * HD);
  k_transpose_cvt<<<dim3(D / 64, (H * HD) / 64), 256, 0, stream>>>(Wo, Wot, H * HD, D);
  k_rope_table<<<S * 128 / 256, 256, 0, stream>>>(pos, tab);

  k_gemm_bt<0><<<dim3(B * S / 128, (H * HD) / 128), 256, 0, stream>>>(
      Xb, Wqt, Qb, nullptr, B * S, H * HD, D);
  k_gemm_bt<3><<<dim3(B * S / 128, (2 * KVH * HD) / 128), 256, 0, stream>>>(
      Xb, Wkvt, Kb, Vf, B * S, 2 * KVH * HD, D);

  // Q scale folds 1/sqrt(HD)=1/16 AND log2(e) (softmax in exp2 domain)
  k_norm_rope<<<B * S * H / 4, 256, 0, stream>>>(Qb, qw, tab, H, 0.0625f * 1.4426950408889634f);
  k_norm_rope_k<<<dim3(S / 64, KVH, B), 256, 0, stream>>>(Kb, Kf, kw, tab);

  k_attn<<<dim3(S / 128, H, B), 256, 0, stream>>>(Qb, Kf, Vf, Ab);

  k_gemm_bt<1><<<dim3(B * S / 128, D / 128), 256, 0, stream>>>(
      Ab, Wot, out, nullptr, B * S, D, H * HD);
}